// Round 6
// baseline (566.634 us; speedup 1.0000x reference)
//
#include <hip/hip_runtime.h>
#include <math.h>

#define NB 4
#define SS 200
#define LT 256
#define DD 256
#define NH 8
#define NLAYER 2
#define FFD 1024
#define BERTD 768
#define NEGINF -1e15f

typedef __attribute__((ext_vector_type(8))) short bf16x8;
typedef __attribute__((ext_vector_type(4))) float f32x4;
typedef __attribute__((ext_vector_type(8))) unsigned short u16x8;

__device__ inline float bf2f(unsigned short h) {
    union { unsigned int u; float f; } v; v.u = ((unsigned int)h) << 16; return v.f;
}
__device__ inline unsigned short f2bf(float x) {
    union { float f; unsigned int u; } v; v.f = x;
    unsigned int r = v.u + 0x7fffu + ((v.u >> 16) & 1u);
    return (unsigned short)(r >> 16);
}
__device__ inline void split2(float x, unsigned short& h, unsigned short& l) {
    h = f2bf(x); l = f2bf(x - bf2f(h));
}

// ---------------- gather combined embed input -> bf16 hi/lo [1024][1024] --------------
__global__ void gather_v3(const int* __restrict__ lattice, const int* __restrict__ bigrams,
                          const int* __restrict__ seq_len, const int* __restrict__ lex_num,
                          const float* __restrict__ bert, const float* __restrict__ lat_t,
                          const float* __restrict__ big_t,
                          unsigned short* __restrict__ Gh, unsigned short* __restrict__ Gl)
{
    const int row = blockIdx.x, t = threadIdx.x;
    const int b = row >> 8, l = row & 255;
    const int sl = seq_len[b], tl = sl + lex_num[b];
    const float mC = (l < sl) ? 1.f : 0.f;
    const float mL = (l >= sl && l < tl) ? 1.f : 0.f;
    const int lat = lattice[row];
    const int big = (l < SS) ? bigrams[b*SS + l] : 0;
    for (int i = t; i < 1024; i += 256) {
        float v;
        if (i < 50)        v = lat_t[lat*50 + i] * mC;
        else if (i < 100)  v = (l < SS) ? big_t[big*50 + (i-50)] * mC : 0.f;
        else if (i < 868)  v = (l < SS) ? bert[(b*SS + l)*BERTD + (i-100)] * mC : 0.f;
        else if (i < 918)  v = lat_t[lat*50 + (i-868)] * mL;
        else if (i == 918) v = mC;
        else if (i == 919) v = mL;
        else               v = 0.f;
        unsigned short hh, ll; split2(v, hh, ll);
        Gh[(size_t)row*1024 + i] = hh; Gl[(size_t)row*1024 + i] = ll;
    }
}

// ---------------- Wcomb[1024][256] f32 = [Wc ; Wl ; bc ; bl ; 0] ----------------------
__global__ void wcomb_kernel(const float* __restrict__ Wc, const float* __restrict__ bc,
                             const float* __restrict__ Wl, const float* __restrict__ bl,
                             float* __restrict__ Wcomb)
{
    const int r = blockIdx.x, t = threadIdx.x;
    float v;
    if (r < 868)       v = Wc[r*DD + t];
    else if (r < 918)  v = Wl[(r-868)*DD + t];
    else if (r == 918) v = bc[t];
    else if (r == 919) v = bl[t];
    else               v = 0.f;
    Wcomb[r*DD + t] = v;
}

// ---------------- PE -> bf16 hi/lo [1088][256] ----------------------------------------
__global__ void pe_v3(unsigned short* __restrict__ PEh, unsigned short* __restrict__ PEl)
{
    const int p = blockIdx.x, t = threadIdx.x;
    float v = 0.f;
    if (p <= 1024) {
        const float fr = expf(-(float)(t & 127) * (9.210340371976184f / 127.0f));
        const float arg = (float)p * fr;
        v = (t < 128) ? sinf(arg) : cosf(arg);
    }
    unsigned short hh, ll; split2(v, hh, ll);
    PEh[p*DD + t] = hh; PEl[p*DD + t] = ll;
}

// ---------------- small packs: bqkv[2][768], bfus4[1024] ------------------------------
__global__ void smallpack(const float* __restrict__ bq, const float* __restrict__ bk,
                          const float* __restrict__ bv, const float* __restrict__ b_fus,
                          float* __restrict__ bqkv, float* __restrict__ bfus4)
{
    const int t = threadIdx.x;
    for (int l = 0; l < NLAYER; ++l) {
        bqkv[l*768 + t]       = bq[l*DD + t];
        bqkv[l*768 + 256 + t] = bk[l*DD + t];
        bqkv[l*768 + 512 + t] = bv[l*DD + t];
    }
    bfus4[t] = b_fus[t];
    bfus4[256 + t] = 0.f; bfus4[512 + t] = 0.f; bfus4[768 + t] = 0.f;
}

// ---------------- bias_vr[l*8+h][e] = sum_d vb[l,h*32+d] * Wr[l][h*32+d][e] -----------
__global__ void vrbias_kernel(const float* __restrict__ vb, const float* __restrict__ Wr,
                              float* __restrict__ bias_vr)
{
    const int lh = blockIdx.x, t = threadIdx.x;
    const int l = lh >> 3, h = lh & 7;
    float acc = 0.f;
    #pragma unroll 8
    for (int d = 0; d < 32; ++d)
        acc += vb[l*DD + h*32 + d] * Wr[(size_t)l*DD*DD + (h*32 + d)*DD + t];
    bias_vr[lh*DD + t] = acc;
}

// ---------------- merged transpose+split of all GEMM weights --------------------------
__global__ void trans_all(const float* __restrict__ Wcomb, const float* __restrict__ Wq,
                          const float* __restrict__ Wk, const float* __restrict__ Wv,
                          const float* __restrict__ Wo, const float* __restrict__ W1,
                          const float* __restrict__ W2, const float* __restrict__ Wfus,
                          const float* __restrict__ Wr,
                          unsigned short* WcombT_h, unsigned short* WcombT_l,
                          unsigned short* WqkvT_h,  unsigned short* WqkvT_l,
                          unsigned short* WoT_h,    unsigned short* WoT_l,
                          unsigned short* W1T_h,    unsigned short* W1T_l,
                          unsigned short* W2T_h,    unsigned short* W2T_l,
                          unsigned short* WfusT_h,  unsigned short* WfusT_l,
                          unsigned short* WrB_h,    unsigned short* WrB_l)
{
    const int z = blockIdx.z, y = blockIdx.y, tx = blockIdx.x, t = threadIdx.x;
    const float* src; unsigned short *dh, *dl; int K, N;
    switch (z) {
        case 0: if (y) return; K = 1024; N = 256; src = Wcomb; dh = WcombT_h; dl = WcombT_l; break;
        case 1: { if (y >= 6) return; int l = y/3, s = y%3; K = 256; N = 256;
                  src = (s==0 ? Wq : s==1 ? Wk : Wv) + l*65536;
                  dh = WqkvT_h + (l*768 + s*256)*256; dl = WqkvT_l + (l*768 + s*256)*256; } break;
        case 2: if (y >= 2) return; K = 256; N = 256;  src = Wo + y*65536;  dh = WoT_h + y*65536;  dl = WoT_l + y*65536;  break;
        case 3: if (y >= 2) return; K = 256; N = 1024; src = W1 + y*262144; dh = W1T_h + y*262144; dl = W1T_l + y*262144; break;
        case 4: if (y >= 2) return; K = 1024; N = 256; src = W2 + y*262144; dh = W2T_h + y*262144; dl = W2T_l + y*262144; break;
        case 5: if (y >= 4) return; K = 256; N = 256;  src = Wfus + y*65536; dh = WfusT_h + y*65536; dl = WfusT_l + y*65536; break;
        case 6: { if (y >= 16) return; int l = y >> 3, h = y & 7; K = 32; N = 256;
                  src = Wr + (size_t)l*65536 + h*32*256;
                  dh = WrB_h + y*8192; dl = WrB_l + y*8192; } break;
        default: return;
    }
    const int tiles_x = N >> 5;
    const int tn = tx % tiles_x, tk = tx / tiles_x;
    if (tk >= (K >> 5)) return;
    __shared__ float s[32][33];
    const int lr = t >> 5, lc = t & 31;
    #pragma unroll
    for (int i = 0; i < 4; ++i)
        s[lr + 8*i][lc] = src[(size_t)(tk*32 + lr + 8*i)*N + tn*32 + lc];
    __syncthreads();
    #pragma unroll
    for (int i = 0; i < 4; ++i) {
        const int n = tn*32 + lr + 8*i, k = tk*32 + lc;
        unsigned short hh, ll; split2(s[lc][lr + 8*i], hh, ll);
        dh[(size_t)n*K + k] = hh;
        dl[(size_t)n*K + k] = ll;
    }
}

// ---------------- MFMA GEMM v3: A pre-split bf16 [M][lda], B pre-split [N][K] ---------
template<int BK, bool RELU, bool EMIT>
__global__ __launch_bounds__(256) void gemm_v3(
    const unsigned short* __restrict__ Ah, const unsigned short* __restrict__ Al,
    const unsigned short* __restrict__ Bh, const unsigned short* __restrict__ Bl,
    const float* __restrict__ bias, const float* __restrict__ resid,
    float* __restrict__ C, unsigned short* __restrict__ Ch, unsigned short* __restrict__ Cl,
    int M, int N, int K, int lda, int ldc, int aZ, int bZ, int cZ, int biasZ)
{
    constexpr int LDK = BK + 8;
    __shared__ unsigned short AhS[64*LDK], AlS[64*LDK];
    __shared__ unsigned short BhS[64*LDK], BlS[64*LDK];
    const int z = blockIdx.z;
    Ah += (size_t)z * aZ; Al += (size_t)z * aZ;
    Bh += (size_t)z * bZ; Bl += (size_t)z * bZ;
    C  += (size_t)z * cZ;
    if (EMIT) { Ch += (size_t)z * cZ; Cl += (size_t)z * cZ; }
    if (bias) bias += (size_t)z * biasZ;

    const int t = threadIdx.x;
    const int row0 = blockIdx.y * 64, col0 = blockIdx.x * 64;
    const int lane = t & 63, w = t >> 6;
    const int wm = w >> 1, wn = w & 1;
    const int fr = lane & 15, fq = lane >> 4;
    const int sr = t >> 2, sc0 = (t & 3) * (BK/4);

    f32x4 acc[2][2];
    #pragma unroll
    for (int i = 0; i < 2; ++i)
        #pragma unroll
        for (int j = 0; j < 2; ++j) acc[i][j] = (f32x4){0.f, 0.f, 0.f, 0.f};

    for (int k0 = 0; k0 < K; k0 += BK) {
        #pragma unroll
        for (int i = 0; i < BK/32; ++i) {
            const int c = sc0 + i*8;
            *(u16x8*)&AhS[sr*LDK + c] = *(const u16x8*)&Ah[(size_t)(row0+sr)*lda + k0 + c];
            *(u16x8*)&AlS[sr*LDK + c] = *(const u16x8*)&Al[(size_t)(row0+sr)*lda + k0 + c];
            *(u16x8*)&BhS[sr*LDK + c] = *(const u16x8*)&Bh[(size_t)(col0+sr)*K + k0 + c];
            *(u16x8*)&BlS[sr*LDK + c] = *(const u16x8*)&Bl[(size_t)(col0+sr)*K + k0 + c];
        }
        __syncthreads();
        #pragma unroll
        for (int ks = 0; ks < BK/32; ++ks) {
            const int ko = ks*32 + fq*8;
            const bf16x8 ah0 = *(const bf16x8*)&AhS[(wm*32 + fr)*LDK + ko];
            const bf16x8 ah1 = *(const bf16x8*)&AhS[(wm*32 + 16 + fr)*LDK + ko];
            const bf16x8 al0 = *(const bf16x8*)&AlS[(wm*32 + fr)*LDK + ko];
            const bf16x8 al1 = *(const bf16x8*)&AlS[(wm*32 + 16 + fr)*LDK + ko];
            #pragma unroll
            for (int nt = 0; nt < 2; ++nt) {
                const int nb = (wn*32 + nt*16 + fr)*LDK + ko;
                const bf16x8 bh = *(const bf16x8*)&BhS[nb];
                const bf16x8 bl = *(const bf16x8*)&BlS[nb];
                acc[0][nt] = __builtin_amdgcn_mfma_f32_16x16x32_bf16(ah0, bh, acc[0][nt], 0, 0, 0);
                acc[0][nt] = __builtin_amdgcn_mfma_f32_16x16x32_bf16(ah0, bl, acc[0][nt], 0, 0, 0);
                acc[0][nt] = __builtin_amdgcn_mfma_f32_16x16x32_bf16(al0, bh, acc[0][nt], 0, 0, 0);
                acc[1][nt] = __builtin_amdgcn_mfma_f32_16x16x32_bf16(ah1, bh, acc[1][nt], 0, 0, 0);
                acc[1][nt] = __builtin_amdgcn_mfma_f32_16x16x32_bf16(ah1, bl, acc[1][nt], 0, 0, 0);
                acc[1][nt] = __builtin_amdgcn_mfma_f32_16x16x32_bf16(al1, bh, acc[1][nt], 0, 0, 0);
            }
        }
        __syncthreads();
    }
    #pragma unroll
    for (int mt = 0; mt < 2; ++mt) {
        #pragma unroll
        for (int nt = 0; nt < 2; ++nt) {
            const int gcol = col0 + wn*32 + nt*16 + fr;
            const float bv = bias ? bias[gcol] : 0.f;
            #pragma unroll
            for (int r = 0; r < 4; ++r) {
                const int grow = row0 + wm*32 + mt*16 + fq*4 + r;
                float v = acc[mt][nt][r] + bv;
                if (resid) v += resid[(size_t)grow*ldc + gcol];
                if (RELU)  v = fmaxf(v, 0.f);
                C[(size_t)grow*ldc + gcol] = v;
                if (EMIT) {
                    unsigned short hh, ll; split2(v, hh, ll);
                    Ch[(size_t)grow*ldc + gcol] = hh;
                    Cl[(size_t)grow*ldc + gcol] = ll;
                }
            }
        }
    }
}

// ---------------- Rcc[p] = relu(sum of 4 segments of Tn[p]) ---------------------------
__global__ void rcc_kernel(const float* __restrict__ Tn, float* __restrict__ Rcc)
{
    const int p = blockIdx.x, t = threadIdx.x;
    const float v = Tn[(size_t)p*1024 + t] + Tn[(size_t)p*1024 + 256 + t]
                  + Tn[(size_t)p*1024 + 512 + t] + Tn[(size_t)p*1024 + 768 + t];
    Rcc[p*DD + t] = fmaxf(v, 0.f);
}

// ---------------- fused attention v3: per (b,q); waves own k-tiles --------------------
__global__ __launch_bounds__(256) void attn_v3(
    const float* __restrict__ qkvb, const float* __restrict__ qr,
    const float* __restrict__ Tn, const float* __restrict__ Rcc,
    const int* __restrict__ pos_s, const int* __restrict__ pos_e,
    const int* __restrict__ seq_len, const int* __restrict__ lex_num,
    const float* __restrict__ u, float* __restrict__ ob,
    unsigned short* __restrict__ obh, unsigned short* __restrict__ obl)
{
    __shared__ float qrl[NH][260];
    __shared__ float qu[256];
    __shared__ float sc[NH][264];
    __shared__ float red[1024];
    const int t = threadIdx.x;
    const int row = blockIdx.x;
    const int b = row >> 8, q = row & 255;
    const int totlen = seq_len[b] + lex_num[b];
    if (q >= SS && q >= totlen) {
        ob[row*DD + t] = 0.f; obh[row*DD + t] = 0; obl[row*DD + t] = 0;
        return;
    }
    qu[t] = qkvb[(size_t)row*768 + t] + u[t];
    #pragma unroll
    for (int h = 0; h < NH; ++h) qrl[h][t] = qr[(size_t)row*2048 + h*256 + t];
    const int ps_q = pos_s[row], pe_q = pos_e[row];
    const int* psb = pos_s + b*LT;
    const int* peb = pos_e + b*LT;
    __syncthreads();

    const int w = t >> 6, lane = t & 63;
    const int kl = lane >> 1, half = lane & 1, e0 = half*128;
    #pragma unroll
    for (int it = 0; it < 2; ++it) {
        const int K0 = (w + it*4) * 32;
        const int kg = K0 + kl;
        if (kg < totlen) {
            float a[8] = {0.f,0.f,0.f,0.f,0.f,0.f,0.f,0.f};
            const int sk = psb[kg], ek = peb[kg];
            if (q < SS && kg < SS) {
                const float4* rp = (const float4*)(Rcc + (ps_q - sk + 512)*DD + e0);
                for (int e4 = 0; e4 < 32; ++e4) {
                    const float4 r4 = rp[e4];
                    #pragma unroll
                    for (int h = 0; h < 8; ++h) {
                        const float4 q4 = *(const float4*)&qrl[h][e0 + e4*4];
                        a[h] += r4.x*q4.x + r4.y*q4.y + r4.z*q4.z + r4.w*q4.w;
                    }
                }
            } else {
                const float4* t0p = (const float4*)(Tn + (size_t)(ps_q - sk + 512)*1024 + e0);
                const float4* t1p = (const float4*)(Tn + (size_t)(ps_q - ek + 512)*1024 + 256 + e0);
                const float4* t2p = (const float4*)(Tn + (size_t)(pe_q - sk + 512)*1024 + 512 + e0);
                const float4* t3p = (const float4*)(Tn + (size_t)(pe_q - ek + 512)*1024 + 768 + e0);
                for (int e4 = 0; e4 < 32; ++e4) {
                    const float4 va = t0p[e4], vb2 = t1p[e4], vc = t2p[e4], vd = t3p[e4];
                    float4 r4;
                    r4.x = fmaxf(va.x + vb2.x + vc.x + vd.x, 0.f);
                    r4.y = fmaxf(va.y + vb2.y + vc.y + vd.y, 0.f);
                    r4.z = fmaxf(va.z + vb2.z + vc.z + vd.z, 0.f);
                    r4.w = fmaxf(va.w + vb2.w + vc.w + vd.w, 0.f);
                    #pragma unroll
                    for (int h = 0; h < 8; ++h) {
                        const float4 q4 = *(const float4*)&qrl[h][e0 + e4*4];
                        a[h] += r4.x*q4.x + r4.y*q4.y + r4.z*q4.z + r4.w*q4.w;
                    }
                }
            }
            {   // AC: this lane covers 4 heads (half0: h0-3, half1: h4-7)
                const float* kp = qkvb + (size_t)(b*LT + kg)*768 + 256;
                #pragma unroll
                for (int hh = 0; hh < 4; ++hh) {
                    const int h = half*4 + hh;
                    float ac = 0.f;
                    #pragma unroll
                    for (int d4 = 0; d4 < 8; ++d4) {
                        const float4 kv = *(const float4*)&kp[h*32 + d4*4];
                        const float4 qv = *(const float4*)&qu[h*32 + d4*4];
                        ac += kv.x*qv.x + kv.y*qv.y + kv.z*qv.z + kv.w*qv.w;
                    }
                    a[h] += ac;
                }
            }
            #pragma unroll
            for (int h = 0; h < 8; ++h) a[h] += __shfl_xor(a[h], 1);
            if (half == 0) {
                #pragma unroll
                for (int h = 0; h < 8; ++h) sc[h][kg] = a[h] * 0.17677669529663687f;
            }
        } else if (half == 0) {
            #pragma unroll
            for (int h = 0; h < 8; ++h) sc[h][kg] = NEGINF;
        }
    }
    __syncthreads();
    {   // softmax: 8 lane-groups of 32, one head each
        const int g = t >> 5, ln = t & 31;
        float vals[8];
        float m = -INFINITY;
        #pragma unroll
        for (int i = 0; i < 8; ++i) {
            const int kidx = ln + 32*i;
            vals[i] = (kidx < totlen) ? sc[g][kidx] : NEGINF;
            m = fmaxf(m, vals[i]);
        }
        #pragma unroll
        for (int off = 16; off >= 1; off >>= 1) m = fmaxf(m, __shfl_xor(m, off, 32));
        float sum = 0.f;
        #pragma unroll
        for (int i = 0; i < 8; ++i) { vals[i] = expf(vals[i] - m); sum += vals[i]; }
        #pragma unroll
        for (int off = 16; off >= 1; off >>= 1) sum += __shfl_xor(sum, off, 32);
        const float inv = 1.0f / sum;
        #pragma unroll
        for (int i = 0; i < 8; ++i) sc[g][ln + 32*i] = vals[i] * inv;
    }
    __syncthreads();
    {   // PV
        const int j4 = (t & 63)*4, kr = t >> 6;
        const int h = j4 >> 5;
        float4 acc = make_float4(0.f, 0.f, 0.f, 0.f);
        const float* vp = qkvb + (size_t)(b*LT)*768 + 512 + j4;
        for (int k = kr; k < totlen; k += 4) {
            const float p = sc[h][k];
            const float4 v = *(const float4*)&vp[(size_t)k*768];
            acc.x += p*v.x; acc.y += p*v.y; acc.z += p*v.z; acc.w += p*v.w;
        }
        *(float4*)&red[kr*256 + j4] = acc;
    }
    __syncthreads();
    {
        const float v = red[t] + red[256 + t] + red[512 + t] + red[768 + t];
        ob[row*DD + t] = v;
        unsigned short hh, ll; split2(v, hh, ll);
        obh[row*DD + t] = hh; obl[row*DD + t] = ll;
    }
}

// ---------------- LayerNorm over last dim (256), optional bf16 emit -------------------
template<bool EMIT>
__global__ void ln_v3(const float* __restrict__ in, const float* __restrict__ g,
                      const float* __restrict__ bb, float* __restrict__ out,
                      unsigned short* __restrict__ oh, unsigned short* __restrict__ ol)
{
    __shared__ float red[4];
    const int t = threadIdx.x, row = blockIdx.x;
    const float v = in[row*DD + t];
    float s = v;
    #pragma unroll
    for (int off = 32; off >= 1; off >>= 1) s += __shfl_xor(s, off, 64);
    if ((t & 63) == 0) red[t >> 6] = s;
    __syncthreads();
    const float m = (red[0] + red[1] + red[2] + red[3]) * (1.0f/256.0f);
    __syncthreads();
    const float d = v - m;
    float s2 = d*d;
    #pragma unroll
    for (int off = 32; off >= 1; off >>= 1) s2 += __shfl_xor(s2, off, 64);
    if ((t & 63) == 0) red[t >> 6] = s2;
    __syncthreads();
    const float var = (red[0] + red[1] + red[2] + red[3]) * (1.0f/256.0f);
    const float o = d * rsqrtf(var + 1e-5f) * g[t] + bb[t];
    out[row*DD + t] = o;
    if (EMIT) {
        unsigned short hh, ll; split2(o, hh, ll);
        oh[row*DD + t] = hh; ol[row*DD + t] = ll;
    }
}

// ---------------- final: logits[b,s] = x[b,s] @ Wout + bout ---------------------------
__global__ void out_kernel(const float* __restrict__ x, const float* __restrict__ Wout,
                           const float* __restrict__ bout, float* __restrict__ out)
{
    __shared__ float xs[256];
    const int t = threadIdx.x, row = blockIdx.x;
    const int b = row / SS, s = row % SS;
    const float* xr = x + (b*LT + s)*DD;
    for (int i = t; i < DD; i += 64) xs[i] = xr[i];
    __syncthreads();
    if (t < 20) {
        float acc = bout[t];
        for (int d = 0; d < DD; ++d) acc += xs[d] * Wout[d*20 + t];
        out[row*20 + t] = acc;
    }
}

extern "C" void kernel_launch(void* const* d_in, const int* in_sizes, int n_in,
                              void* d_out, int out_size, void* d_ws, size_t ws_size,
                              hipStream_t stream)
{
    const int*   lattice = (const int*)d_in[0];
    const int*   bigrams = (const int*)d_in[1];
    const int*   seq_len = (const int*)d_in[2];
    const int*   lex_num = (const int*)d_in[3];
    const int*   pos_s   = (const int*)d_in[4];
    const int*   pos_e   = (const int*)d_in[5];
    const float* bert    = (const float*)d_in[7];
    const float* lat_t   = (const float*)d_in[8];
    const float* big_t   = (const float*)d_in[9];
    const float* Wc      = (const float*)d_in[10];
    const float* bc      = (const float*)d_in[11];
    const float* Wl      = (const float*)d_in[12];
    const float* bl      = (const float*)d_in[13];
    const float* W_fus   = (const float*)d_in[14];
    const float* b_fus   = (const float*)d_in[15];
    const float* Wq      = (const float*)d_in[16];
    const float* bq      = (const float*)d_in[17];
    const float* Wk      = (const float*)d_in[18];
    const float* bk      = (const float*)d_in[19];
    const float* Wv      = (const float*)d_in[20];
    const float* bv      = (const float*)d_in[21];
    const float* Wr      = (const float*)d_in[22];
    /* d_in[23] br: dropped — constant over k, softmax shift-invariant */
    const float* u_bias  = (const float*)d_in[24];
    const float* v_bias  = (const float*)d_in[25];
    const float* Wo      = (const float*)d_in[26];
    const float* bo      = (const float*)d_in[27];
    const float* ln1g    = (const float*)d_in[28];
    const float* ln1b    = (const float*)d_in[29];
    const float* W1      = (const float*)d_in[30];
    const float* b1      = (const float*)d_in[31];
    const float* W2      = (const float*)d_in[32];
    const float* b2      = (const float*)d_in[33];
    const float* ln2g    = (const float*)d_in[34];
    const float* ln2b    = (const float*)d_in[35];
    const float* Wout    = (const float*)d_in[36];
    const float* bout    = (const float*)d_in[37];

    float* ws = (float*)d_ws;
    float* qkvb = ws;  ws += NB*LT*768;
    float* ob   = ws;  ws += NB*LT*DD;
    float* t1   = ws;  ws += NB*LT*DD;        // also aliases PEh
    float* x2   = ws;  ws += NB*LT*DD;
    float* t2   = ws;  ws += NB*LT*DD;        // also aliases PEl
    float* hb   = ws;  ws += NB*LT*FFD;
    float* x    = ws;  ws += NB*LT*DD;
    float* Tn   = ws;  ws += 1088*1024;
    float* Rcc  = ws;  ws += 1025*DD;
    float* qr   = ws;  ws += NB*LT*NH*DD;
    float* Wcomb= ws;  ws += 1024*DD;
    float* bqkv = ws;  ws += NLAYER*768;
    float* bfus4= ws;  ws += 1024;
    float* bias_vr = ws; ws += NLAYER*NH*DD;
    unsigned short* us = (unsigned short*)ws;
    unsigned short* xh  = us; us += 1024*256;
    unsigned short* xl  = us; us += 1024*256;
    unsigned short* x2h = us; us += 1024*256;
    unsigned short* x2l = us; us += 1024*256;
    unsigned short* qkvbh = us; us += 1024*768;
    unsigned short* qkvbl = us; us += 1024*768;
    unsigned short* hbh = us; us += 1024*1024;
    unsigned short* hbl = us; us += 1024*1024;
    unsigned short* obh = us; us += 1024*256;
    unsigned short* obl = us; us += 1024*256;
    unsigned short* WcombT_h = us; us += 256*1024;
    unsigned short* WcombT_l = us; us += 256*1024;
    unsigned short* WqkvT_h  = us; us += NLAYER*768*256;
    unsigned short* WqkvT_l  = us; us += NLAYER*768*256;
    unsigned short* WoT_h    = us; us += NLAYER*256*256;
    unsigned short* WoT_l    = us; us += NLAYER*256*256;
    unsigned short* W1T_h    = us; us += NLAYER*1024*256;
    unsigned short* W1T_l    = us; us += NLAYER*1024*256;
    unsigned short* W2T_h    = us; us += NLAYER*256*1024;
    unsigned short* W2T_l    = us; us += NLAYER*256*1024;
    unsigned short* WfusT_h  = us; us += 1024*256;
    unsigned short* WfusT_l  = us; us += 1024*256;
    unsigned short* WrB_h    = us; us += NLAYER*NH*256*32;
    unsigned short* WrB_l    = us; us += NLAYER*NH*256*32;
    // aliases (timeline-disjoint):
    unsigned short* Gh  = hbh;                 // [1024][1024], dead before W1 gemm
    unsigned short* Gl  = hbl;
    unsigned short* PEh = (unsigned short*)t1; // [1088][256], dead before layer loop
    unsigned short* PEl = (unsigned short*)t2;

    const int M = NB*LT;

    gather_v3<<<M, 256, 0, stream>>>(lattice, bigrams, seq_len, lex_num,
                                     bert, lat_t, big_t, Gh, Gl);
    wcomb_kernel<<<1024, 256, 0, stream>>>(Wc, bc, Wl, bl, Wcomb);
    pe_v3<<<1088, 256, 0, stream>>>(PEh, PEl);
    smallpack<<<1, 256, 0, stream>>>(bq, bk, bv, b_fus, bqkv, bfus4);
    vrbias_kernel<<<NLAYER*NH, 256, 0, stream>>>(v_bias, Wr, bias_vr);
    trans_all<<<dim3(256, 16, 7), 256, 0, stream>>>(Wcomb, Wq, Wk, Wv, Wo, W1, W2, W_fus, Wr,
        WcombT_h, WcombT_l, WqkvT_h, WqkvT_l, WoT_h, WoT_l,
        W1T_h, W1T_l, W2T_h, W2T_l, WfusT_h, WfusT_l, WrB_h, WrB_l);

    // Tn = PE @ W_fus (4 tables as column segments) + bfus4
    gemm_v3<64,false,false><<<dim3(16, 17), 256, 0, stream>>>(
        PEh, PEl, WfusT_h, WfusT_l, bfus4, nullptr, Tn, nullptr, nullptr,
        1088, 1024, 256, 256, 1024, 0, 0, 0, 0);
    rcc_kernel<<<1025, 256, 0, stream>>>(Tn, Rcc);

    // embed: x = G @ Wcomb
    gemm_v3<64,false,true><<<dim3(4, 16), 256, 0, stream>>>(
        Gh, Gl, WcombT_h, WcombT_l, nullptr, nullptr, x, xh, xl,
        M, 256, 1024, 1024, 256, 0, 0, 0, 0);

    for (int l = 0; l < NLAYER; ++l) {
        gemm_v3<64,false,true><<<dim3(12, 16), 256, 0, stream>>>(
            xh, xl, WqkvT_h + l*768*256, WqkvT_l + l*768*256, bqkv + l*768, nullptr,
            qkvb, qkvbh, qkvbl, M, 768, 256, 256, 768, 0, 0, 0, 0);
        // qr[row][h][e] = (Q_h) @ Wr_h + bias_vr  (block-diag MFMA, z = head)
        gemm_v3<32,false,false><<<dim3(4, 16, 8), 256, 0, stream>>>(
            qkvbh, qkvbl, WrB_h + l*8*8192, WrB_l + l*8*8192, bias_vr + l*8*256, nullptr,
            qr, nullptr, nullptr, M, 256, 32, 768, 2048, 32, 8192, 256, 256);
        attn_v3<<<M, 256, 0, stream>>>(qkvb, qr, Tn, Rcc, pos_s, pos_e,
                                       seq_len, lex_num, u_bias + l*DD, ob, obh, obl);
        gemm_v3<64,false,false><<<dim3(4, 16), 256, 0, stream>>>(
            obh, obl, WoT_h + l*65536, WoT_l + l*65536, bo + l*DD, x,
            t1, nullptr, nullptr, M, 256, 256, 256, 256, 0, 0, 0, 0);
        ln_v3<true><<<M, 256, 0, stream>>>(t1, ln1g + l*DD, ln1b + l*DD, x2, x2h, x2l);
        gemm_v3<64,true,true><<<dim3(16, 16), 256, 0, stream>>>(
            x2h, x2l, W1T_h + l*262144, W1T_l + l*262144, b1 + l*FFD, nullptr,
            hb, hbh, hbl, M, FFD, 256, 256, 1024, 0, 0, 0, 0);
        gemm_v3<64,false,false><<<dim3(4, 16), 256, 0, stream>>>(
            hbh, hbl, W2T_h + l*262144, W2T_l + l*262144, b2 + l*DD, x2,
            t2, nullptr, nullptr, M, 256, 1024, 1024, 256, 0, 0, 0, 0);
        ln_v3<true><<<M, 256, 0, stream>>>(t2, ln2g + l*DD, ln2b + l*DD, x, xh, xl);
    }
    out_kernel<<<NB*SS, 64, 0, stream>>>(x, Wout, bout, (float*)d_out);
}

// Round 8
// 492.638 us; speedup vs baseline: 1.1502x; 1.1502x over previous
//
#include <hip/hip_runtime.h>
#include <math.h>

#define NB 4
#define SS 200
#define LT 256
#define DD 256
#define NH 8
#define NLAYER 2
#define FFD 1024
#define BERTD 768
#define NEGINF -1e15f
#define SCL 0.17677669529663687f

typedef __attribute__((ext_vector_type(8))) short bf16x8;
typedef __attribute__((ext_vector_type(4))) float f32x4;
typedef __attribute__((ext_vector_type(8))) unsigned short u16x8;

__device__ inline float bf2f(unsigned short h) {
    union { unsigned int u; float f; } v; v.u = ((unsigned int)h) << 16; return v.f;
}
__device__ inline unsigned short f2bf(float x) {
    union { float f; unsigned int u; } v; v.f = x;
    unsigned int r = v.u + 0x7fffu + ((v.u >> 16) & 1u);
    return (unsigned short)(r >> 16);
}
__device__ inline void split2(float x, unsigned short& h, unsigned short& l) {
    h = f2bf(x); l = f2bf(x - bf2f(h));
}

// ---------------- gather combined embed input -> bf16 hi/lo [1024][1024] --------------
__global__ void gather_v3(const int* __restrict__ lattice, const int* __restrict__ bigrams,
                          const int* __restrict__ seq_len, const int* __restrict__ lex_num,
                          const float* __restrict__ bert, const float* __restrict__ lat_t,
                          const float* __restrict__ big_t,
                          unsigned short* __restrict__ Gh, unsigned short* __restrict__ Gl)
{
    const int row = blockIdx.x, t = threadIdx.x;
    const int b = row >> 8, l = row & 255;
    const int sl = seq_len[b], tl = sl + lex_num[b];
    const float mC = (l < sl) ? 1.f : 0.f;
    const float mL = (l >= sl && l < tl) ? 1.f : 0.f;
    const int lat = lattice[row];
    const int big = (l < SS) ? bigrams[b*SS + l] : 0;
    for (int i = t; i < 1024; i += 256) {
        float v;
        if (i < 50)        v = lat_t[lat*50 + i] * mC;
        else if (i < 100)  v = (l < SS) ? big_t[big*50 + (i-50)] * mC : 0.f;
        else if (i < 868)  v = (l < SS) ? bert[(b*SS + l)*BERTD + (i-100)] * mC : 0.f;
        else if (i < 918)  v = lat_t[lat*50 + (i-868)] * mL;
        else if (i == 918) v = mC;
        else if (i == 919) v = mL;
        else               v = 0.f;
        unsigned short hh, ll; split2(v, hh, ll);
        Gh[(size_t)row*1024 + i] = hh; Gl[(size_t)row*1024 + i] = ll;
    }
}

// ---------------- Wcomb[1024][256] f32 = [Wc ; Wl ; bc ; bl ; 0] ----------------------
__global__ void wcomb_kernel(const float* __restrict__ Wc, const float* __restrict__ bc,
                             const float* __restrict__ Wl, const float* __restrict__ bl,
                             float* __restrict__ Wcomb)
{
    const int r = blockIdx.x, t = threadIdx.x;
    float v;
    if (r < 868)       v = Wc[r*DD + t];
    else if (r < 918)  v = Wl[(r-868)*DD + t];
    else if (r == 918) v = bc[t];
    else if (r == 919) v = bl[t];
    else               v = 0.f;
    Wcomb[r*DD + t] = v;
}

// ---------------- PE -> bf16 hi/lo [1088][256] ----------------------------------------
__global__ void pe_v3(unsigned short* __restrict__ PEh, unsigned short* __restrict__ PEl)
{
    const int p = blockIdx.x, t = threadIdx.x;
    float v = 0.f;
    if (p <= 1024) {
        const float fr = expf(-(float)(t & 127) * (9.210340371976184f / 127.0f));
        const float arg = (float)p * fr;
        v = (t < 128) ? sinf(arg) : cosf(arg);
    }
    unsigned short hh, ll; split2(v, hh, ll);
    PEh[p*DD + t] = hh; PEl[p*DD + t] = ll;
}

// ---------------- small packs: bqkv[2][768], bfus4[1024] ------------------------------
__global__ void smallpack(const float* __restrict__ bq, const float* __restrict__ bk,
                          const float* __restrict__ bv, const float* __restrict__ b_fus,
                          float* __restrict__ bqkv, float* __restrict__ bfus4)
{
    const int t = threadIdx.x;
    for (int l = 0; l < NLAYER; ++l) {
        bqkv[l*768 + t]       = bq[l*DD + t];
        bqkv[l*768 + 256 + t] = bk[l*DD + t];
        bqkv[l*768 + 512 + t] = bv[l*DD + t];
    }
    bfus4[t] = b_fus[t];
    bfus4[256 + t] = 0.f; bfus4[512 + t] = 0.f; bfus4[768 + t] = 0.f;
}

// ---------------- bias_vr[l*8+h][e] = sum_d vb[l,h*32+d] * Wr[l][h*32+d][e] -----------
__global__ void vrbias_kernel(const float* __restrict__ vb, const float* __restrict__ Wr,
                              float* __restrict__ bias_vr)
{
    const int lh = blockIdx.x, t = threadIdx.x;
    const int l = lh >> 3, h = lh & 7;
    float acc = 0.f;
    #pragma unroll 8
    for (int d = 0; d < 32; ++d)
        acc += vb[l*DD + h*32 + d] * Wr[(size_t)l*DD*DD + (h*32 + d)*DD + t];
    bias_vr[lh*DD + t] = acc;
}

// ---------------- merged transpose+split of all GEMM weights --------------------------
__global__ void trans_all(const float* __restrict__ Wcomb, const float* __restrict__ Wq,
                          const float* __restrict__ Wk, const float* __restrict__ Wv,
                          const float* __restrict__ Wo, const float* __restrict__ W1,
                          const float* __restrict__ W2, const float* __restrict__ Wfus,
                          const float* __restrict__ Wr,
                          unsigned short* WcombT_h, unsigned short* WcombT_l,
                          unsigned short* WqkvT_h,  unsigned short* WqkvT_l,
                          unsigned short* WoT_h,    unsigned short* WoT_l,
                          unsigned short* W1T_h,    unsigned short* W1T_l,
                          unsigned short* W2T_h,    unsigned short* W2T_l,
                          unsigned short* WfusT_h,  unsigned short* WfusT_l,
                          unsigned short* WrB_h,    unsigned short* WrB_l)
{
    const int z = blockIdx.z, y = blockIdx.y, tx = blockIdx.x, t = threadIdx.x;
    const float* src; unsigned short *dh, *dl; int K, N;
    switch (z) {
        case 0: if (y) return; K = 1024; N = 256; src = Wcomb; dh = WcombT_h; dl = WcombT_l; break;
        case 1: { if (y >= 6) return; int l = y/3, s = y%3; K = 256; N = 256;
                  src = (s==0 ? Wq : s==1 ? Wk : Wv) + l*65536;
                  dh = WqkvT_h + (l*768 + s*256)*256; dl = WqkvT_l + (l*768 + s*256)*256; } break;
        case 2: if (y >= 2) return; K = 256; N = 256;  src = Wo + y*65536;  dh = WoT_h + y*65536;  dl = WoT_l + y*65536;  break;
        case 3: if (y >= 2) return; K = 256; N = 1024; src = W1 + y*262144; dh = W1T_h + y*262144; dl = W1T_l + y*262144; break;
        case 4: if (y >= 2) return; K = 1024; N = 256; src = W2 + y*262144; dh = W2T_h + y*262144; dl = W2T_l + y*262144; break;
        case 5: if (y >= 4) return; K = 256; N = 256;  src = Wfus + y*65536; dh = WfusT_h + y*65536; dl = WfusT_l + y*65536; break;
        case 6: { if (y >= 16) return; int l = y >> 3, h = y & 7; K = 32; N = 256;
                  src = Wr + (size_t)l*65536 + h*32*256;
                  dh = WrB_h + y*8192; dl = WrB_l + y*8192; } break;
        default: return;
    }
    const int tiles_x = N >> 5;
    const int tn = tx % tiles_x, tk = tx / tiles_x;
    if (tk >= (K >> 5)) return;
    __shared__ float s[32][33];
    const int lr = t >> 5, lc = t & 31;
    #pragma unroll
    for (int i = 0; i < 4; ++i)
        s[lr + 8*i][lc] = src[(size_t)(tk*32 + lr + 8*i)*N + tn*32 + lc];
    __syncthreads();
    #pragma unroll
    for (int i = 0; i < 4; ++i) {
        const int n = tn*32 + lr + 8*i, k = tk*32 + lc;
        unsigned short hh, ll; split2(s[lc][lr + 8*i], hh, ll);
        dh[(size_t)n*K + k] = hh;
        dl[(size_t)n*K + k] = ll;
    }
}

// ---------------- MFMA GEMM v3: A pre-split bf16 [M][lda], B pre-split [N][K] ---------
template<int BK, bool RELU, bool EMIT>
__global__ __launch_bounds__(256) void gemm_v3(
    const unsigned short* __restrict__ Ah, const unsigned short* __restrict__ Al,
    const unsigned short* __restrict__ Bh, const unsigned short* __restrict__ Bl,
    const float* __restrict__ bias, const float* __restrict__ resid,
    float* __restrict__ C, unsigned short* __restrict__ Ch, unsigned short* __restrict__ Cl,
    int M, int N, int K, int lda, int ldc, int aZ, int bZ, int cZ, int biasZ)
{
    constexpr int LDK = BK + 8;
    __shared__ unsigned short AhS[64*LDK], AlS[64*LDK];
    __shared__ unsigned short BhS[64*LDK], BlS[64*LDK];
    const int z = blockIdx.z;
    Ah += (size_t)z * aZ; Al += (size_t)z * aZ;
    Bh += (size_t)z * bZ; Bl += (size_t)z * bZ;
    C  += (size_t)z * cZ;
    if (EMIT) { Ch += (size_t)z * cZ; Cl += (size_t)z * cZ; }
    if (bias) bias += (size_t)z * biasZ;

    const int t = threadIdx.x;
    const int row0 = blockIdx.y * 64, col0 = blockIdx.x * 64;
    const int lane = t & 63, w = t >> 6;
    const int wm = w >> 1, wn = w & 1;
    const int fr = lane & 15, fq = lane >> 4;
    const int sr = t >> 2, sc0 = (t & 3) * (BK/4);

    f32x4 acc[2][2];
    #pragma unroll
    for (int i = 0; i < 2; ++i)
        #pragma unroll
        for (int j = 0; j < 2; ++j) acc[i][j] = (f32x4){0.f, 0.f, 0.f, 0.f};

    for (int k0 = 0; k0 < K; k0 += BK) {
        #pragma unroll
        for (int i = 0; i < BK/32; ++i) {
            const int c = sc0 + i*8;
            *(u16x8*)&AhS[sr*LDK + c] = *(const u16x8*)&Ah[(size_t)(row0+sr)*lda + k0 + c];
            *(u16x8*)&AlS[sr*LDK + c] = *(const u16x8*)&Al[(size_t)(row0+sr)*lda + k0 + c];
            *(u16x8*)&BhS[sr*LDK + c] = *(const u16x8*)&Bh[(size_t)(col0+sr)*K + k0 + c];
            *(u16x8*)&BlS[sr*LDK + c] = *(const u16x8*)&Bl[(size_t)(col0+sr)*K + k0 + c];
        }
        __syncthreads();
        #pragma unroll
        for (int ks = 0; ks < BK/32; ++ks) {
            const int ko = ks*32 + fq*8;
            const bf16x8 ah0 = *(const bf16x8*)&AhS[(wm*32 + fr)*LDK + ko];
            const bf16x8 ah1 = *(const bf16x8*)&AhS[(wm*32 + 16 + fr)*LDK + ko];
            const bf16x8 al0 = *(const bf16x8*)&AlS[(wm*32 + fr)*LDK + ko];
            const bf16x8 al1 = *(const bf16x8*)&AlS[(wm*32 + 16 + fr)*LDK + ko];
            #pragma unroll
            for (int nt = 0; nt < 2; ++nt) {
                const int nb = (wn*32 + nt*16 + fr)*LDK + ko;
                const bf16x8 bh = *(const bf16x8*)&BhS[nb];
                const bf16x8 bl = *(const bf16x8*)&BlS[nb];
                acc[0][nt] = __builtin_amdgcn_mfma_f32_16x16x32_bf16(ah0, bh, acc[0][nt], 0, 0, 0);
                acc[0][nt] = __builtin_amdgcn_mfma_f32_16x16x32_bf16(ah0, bl, acc[0][nt], 0, 0, 0);
                acc[0][nt] = __builtin_amdgcn_mfma_f32_16x16x32_bf16(al0, bh, acc[0][nt], 0, 0, 0);
                acc[1][nt] = __builtin_amdgcn_mfma_f32_16x16x32_bf16(ah1, bh, acc[1][nt], 0, 0, 0);
                acc[1][nt] = __builtin_amdgcn_mfma_f32_16x16x32_bf16(ah1, bl, acc[1][nt], 0, 0, 0);
                acc[1][nt] = __builtin_amdgcn_mfma_f32_16x16x32_bf16(al1, bh, acc[1][nt], 0, 0, 0);
            }
        }
        __syncthreads();
    }
    #pragma unroll
    for (int mt = 0; mt < 2; ++mt) {
        #pragma unroll
        for (int nt = 0; nt < 2; ++nt) {
            const int gcol = col0 + wn*32 + nt*16 + fr;
            const float bv = bias ? bias[gcol] : 0.f;
            #pragma unroll
            for (int r = 0; r < 4; ++r) {
                const int grow = row0 + wm*32 + mt*16 + fq*4 + r;
                float v = acc[mt][nt][r] + bv;
                if (resid) v += resid[(size_t)grow*ldc + gcol];
                if (RELU)  v = fmaxf(v, 0.f);
                C[(size_t)grow*ldc + gcol] = v;
                if (EMIT) {
                    unsigned short hh, ll; split2(v, hh, ll);
                    Ch[(size_t)grow*ldc + gcol] = hh;
                    Cl[(size_t)grow*ldc + gcol] = ll;
                }
            }
        }
    }
}

// ---------------- Rcc split bf16: relu(sum of 4 segments of Tn[p]) --------------------
__global__ void rcc_split(const float* __restrict__ Tn,
                          unsigned short* __restrict__ Rh, unsigned short* __restrict__ Rl)
{
    const int p = blockIdx.x, t = threadIdx.x;
    const float v = Tn[(size_t)p*1024 + t] + Tn[(size_t)p*1024 + 256 + t]
                  + Tn[(size_t)p*1024 + 512 + t] + Tn[(size_t)p*1024 + 768 + t];
    unsigned short hh, ll; split2(fmaxf(v, 0.f), hh, ll);
    Rh[p*DD + t] = hh; Rl[p*DD + t] = ll;
}

// ---------------- fused attention v4: coalesced gather + Dcc char-char shortcut -------
__global__ __launch_bounds__(256) void attn_v4(
    const float* __restrict__ qkvb, const float* __restrict__ qr,
    const float* __restrict__ Tn, const float* __restrict__ Dcc,
    const int* __restrict__ pos_s, const int* __restrict__ pos_e,
    const int* __restrict__ seq_len, const int* __restrict__ lex_num,
    const float* __restrict__ u, float* __restrict__ ob,
    unsigned short* __restrict__ obh, unsigned short* __restrict__ obl)
{
    __shared__ float qu[256];
    __shared__ float qrl[NH][260];
    __shared__ float sc[NH][264];
    __shared__ float acb[NH][264];
    __shared__ float relb[32][260];
    __shared__ float red[2048];
    float* DccL = &relb[0][0];               // phase-1 alias (8*200 < 32*260)

    const int t = threadIdx.x, row = blockIdx.x;
    const int b = row >> 8, q = row & 255;
    const int totlen = seq_len[b] + lex_num[b];
    if (q >= SS && q >= totlen) {
        ob[row*DD + t] = 0.f; obh[row*DD + t] = 0; obl[row*DD + t] = 0;
        return;
    }
    const bool qc = (q < SS);
    const int gstart = qc ? SS : 0;          // first k needing 4-table gather

    qu[t] = qkvb[(size_t)row*768 + t] + u[t];
    if (totlen > gstart) {
        #pragma unroll
        for (int h = 0; h < NH; ++h) qrl[h][t] = qr[(size_t)row*2048 + h*256 + t];
    }
    if (qc && t < SS) {
        #pragma unroll
        for (int h = 0; h < NH; ++h)
            DccL[h*SS + t] = Dcc[((size_t)h*1024 + row)*448 + q + t];
    }
    const int ps_q = pos_s[row], pe_q = pos_e[row];
    const int* psb = pos_s + b*LT;
    const int* peb = pos_e + b*LT;
    __syncthreads();

    {   // phase 1: AC for all k; full score for char-char via Dcc
        const int h = t & 7, k0 = t >> 3;
        const float4* qp = (const float4*)&qu[h*32];
        #pragma unroll
        for (int pass = 0; pass < 8; ++pass) {
            const int kg = pass*32 + k0;
            if (kg < totlen) {
                const float4* kp = (const float4*)&qkvb[(size_t)(b*LT + kg)*768 + 256 + h*32];
                float ac = 0.f;
                #pragma unroll
                for (int d4 = 0; d4 < 8; ++d4) {
                    const float4 kv = kp[d4], qv = qp[d4];
                    ac += kv.x*qv.x + kv.y*qv.y + kv.z*qv.z + kv.w*qv.w;
                }
                if (qc && kg < SS) sc[h][kg] = (ac + DccL[h*SS + (SS-1) - kg]) * SCL;
                else               acb[h][kg] = ac;
            } else {
                sc[h][kg] = NEGINF;
            }
        }
    }
    __syncthreads();

    // phase 2: gather tiles for lex-involved rows only
    const int gs0 = gstart & ~31;
    for (int K0 = gs0; K0 < totlen; K0 += 32) {
        {   // coalesced staging: 8 threads per row build one rel row
            const int r = t >> 3, c4 = (t & 7)*4;
            const int kg = K0 + r;
            if (kg >= gstart && kg < totlen) {
                const int sk = psb[kg], ek = peb[kg];
                const float* t0 = Tn + (size_t)(ps_q - sk + 512)*1024;
                const float* t1 = Tn + (size_t)(ps_q - ek + 512)*1024 + 256;
                const float* t2 = Tn + (size_t)(pe_q - sk + 512)*1024 + 512;
                const float* t3 = Tn + (size_t)(pe_q - ek + 512)*1024 + 768;
                #pragma unroll
                for (int i = 0; i < 8; ++i) {
                    const int e = i*32 + c4;
                    const float4 a = *(const float4*)&t0[e];
                    const float4 bb = *(const float4*)&t1[e];
                    const float4 c = *(const float4*)&t2[e];
                    const float4 d = *(const float4*)&t3[e];
                    float4 v;
                    v.x = fmaxf(a.x + bb.x + c.x + d.x, 0.f);
                    v.y = fmaxf(a.y + bb.y + c.y + d.y, 0.f);
                    v.z = fmaxf(a.z + bb.z + c.z + d.z, 0.f);
                    v.w = fmaxf(a.w + bb.w + c.w + d.w, 0.f);
                    *(float4*)&relb[r][e] = v;
                }
            }
        }
        __syncthreads();
        {   // BD partials: thread (k=dk, e-seg) x 8 heads
            const int dk = t & 31, seg = t >> 5;
            const int kg = K0 + dk;
            if (kg >= gstart && kg < totlen) {
                float a[8] = {0.f,0.f,0.f,0.f,0.f,0.f,0.f,0.f};
                const int e0 = seg*32;
                #pragma unroll
                for (int e4 = 0; e4 < 8; ++e4) {
                    const float4 r4 = *(const float4*)&relb[dk][e0 + e4*4];
                    #pragma unroll
                    for (int h = 0; h < 8; ++h) {
                        const float4 q4 = *(const float4*)&qrl[h][e0 + e4*4];
                        a[h] += r4.x*q4.x + r4.y*q4.y + r4.z*q4.z + r4.w*q4.w;
                    }
                }
                float4* rb = (float4*)&red[(seg*32 + dk)*8];
                rb[0] = make_float4(a[0], a[1], a[2], a[3]);
                rb[1] = make_float4(a[4], a[5], a[6], a[7]);
            }
        }
        __syncthreads();
        {   // reduce + combine with AC
            const int k = t >> 3, h = t & 7;
            const int kg = K0 + k;
            if (kg >= gstart && kg < totlen) {
                float s = 0.f;
                #pragma unroll
                for (int g = 0; g < 8; ++g) s += red[g*256 + t];
                sc[h][kg] = (s + acb[h][kg]) * SCL;
            }
        }
        __syncthreads();
    }

    {   // softmax: 8 lane-groups of 32, one head each
        const int g = t >> 5, ln = t & 31;
        float vals[8];
        float m = -INFINITY;
        #pragma unroll
        for (int i = 0; i < 8; ++i) {
            const int kidx = ln + 32*i;
            vals[i] = (kidx < totlen) ? sc[g][kidx] : NEGINF;
            m = fmaxf(m, vals[i]);
        }
        #pragma unroll
        for (int off = 16; off >= 1; off >>= 1) m = fmaxf(m, __shfl_xor(m, off, 32));
        float sum = 0.f;
        #pragma unroll
        for (int i = 0; i < 8; ++i) { vals[i] = expf(vals[i] - m); sum += vals[i]; }
        #pragma unroll
        for (int off = 16; off >= 1; off >>= 1) sum += __shfl_xor(sum, off, 32);
        const float inv = 1.0f / sum;
        #pragma unroll
        for (int i = 0; i < 8; ++i) sc[g][ln + 32*i] = vals[i] * inv;
    }
    __syncthreads();
    {   // PV
        const int j4 = (t & 63)*4, kr = t >> 6;
        const int h = j4 >> 5;
        float4 acc = make_float4(0.f, 0.f, 0.f, 0.f);
        const float* vp = qkvb + (size_t)(b*LT)*768 + 512 + j4;
        for (int k = kr; k < totlen; k += 4) {
            const float p = sc[h][k];
            const float4 v = *(const float4*)&vp[(size_t)k*768];
            acc.x += p*v.x; acc.y += p*v.y; acc.z += p*v.z; acc.w += p*v.w;
        }
        *(float4*)&red[kr*256 + j4] = acc;
    }
    __syncthreads();
    {
        const float v = red[t] + red[256 + t] + red[512 + t] + red[768 + t];
        ob[row*DD + t] = v;
        unsigned short hh, ll; split2(v, hh, ll);
        obh[row*DD + t] = hh; obl[row*DD + t] = ll;
    }
}

// ---------------- LayerNorm over last dim (256), optional bf16 emit -------------------
template<bool EMIT>
__global__ void ln_v3(const float* __restrict__ in, const float* __restrict__ g,
                      const float* __restrict__ bb, float* __restrict__ out,
                      unsigned short* __restrict__ oh, unsigned short* __restrict__ ol)
{
    __shared__ float red[4];
    const int t = threadIdx.x, row = blockIdx.x;
    const float v = in[row*DD + t];
    float s = v;
    #pragma unroll
    for (int off = 32; off >= 1; off >>= 1) s += __shfl_xor(s, off, 64);
    if ((t & 63) == 0) red[t >> 6] = s;
    __syncthreads();
    const float m = (red[0] + red[1] + red[2] + red[3]) * (1.0f/256.0f);
    __syncthreads();
    const float d = v - m;
    float s2 = d*d;
    #pragma unroll
    for (int off = 32; off >= 1; off >>= 1) s2 += __shfl_xor(s2, off, 64);
    if ((t & 63) == 0) red[t >> 6] = s2;
    __syncthreads();
    const float var = (red[0] + red[1] + red[2] + red[3]) * (1.0f/256.0f);
    const float o = d * rsqrtf(var + 1e-5f) * g[t] + bb[t];
    out[row*DD + t] = o;
    if (EMIT) {
        unsigned short hh, ll; split2(o, hh, ll);
        oh[row*DD + t] = hh; ol[row*DD + t] = ll;
    }
}

// ---------------- final: logits[b,s] = x[b,s] @ Wout + bout ---------------------------
__global__ void out_kernel(const float* __restrict__ x, const float* __restrict__ Wout,
                           const float* __restrict__ bout, float* __restrict__ out)
{
    __shared__ float xs[256];
    const int t = threadIdx.x, row = blockIdx.x;
    const int b = row / SS, s = row % SS;
    const float* xr = x + (b*LT + s)*DD;
    for (int i = t; i < DD; i += 64) xs[i] = xr[i];
    __syncthreads();
    if (t < 20) {
        float acc = bout[t];
        for (int d = 0; d < DD; ++d) acc += xs[d] * Wout[d*20 + t];
        out[row*20 + t] = acc;
    }
}

extern "C" void kernel_launch(void* const* d_in, const int* in_sizes, int n_in,
                              void* d_out, int out_size, void* d_ws, size_t ws_size,
                              hipStream_t stream)
{
    const int*   lattice = (const int*)d_in[0];
    const int*   bigrams = (const int*)d_in[1];
    const int*   seq_len = (const int*)d_in[2];
    const int*   lex_num = (const int*)d_in[3];
    const int*   pos_s   = (const int*)d_in[4];
    const int*   pos_e   = (const int*)d_in[5];
    const float* bert    = (const float*)d_in[7];
    const float* lat_t   = (const float*)d_in[8];
    const float* big_t   = (const float*)d_in[9];
    const float* Wc      = (const float*)d_in[10];
    const float* bc      = (const float*)d_in[11];
    const float* Wl      = (const float*)d_in[12];
    const float* bl      = (const float*)d_in[13];
    const float* W_fus   = (const float*)d_in[14];
    const float* b_fus   = (const float*)d_in[15];
    const float* Wq      = (const float*)d_in[16];
    const float* bq      = (const float*)d_in[17];
    const float* Wk      = (const float*)d_in[18];
    const float* bk      = (const float*)d_in[19];
    const float* Wv      = (const float*)d_in[20];
    const float* bv      = (const float*)d_in[21];
    const float* Wr      = (const float*)d_in[22];
    /* d_in[23] br: dropped — constant over k, softmax shift-invariant */
    const float* u_bias  = (const float*)d_in[24];
    const float* v_bias  = (const float*)d_in[25];
    const float* Wo      = (const float*)d_in[26];
    const float* bo      = (const float*)d_in[27];
    const float* ln1g    = (const float*)d_in[28];
    const float* ln1b    = (const float*)d_in[29];
    const float* W1      = (const float*)d_in[30];
    const float* b1      = (const float*)d_in[31];
    const float* W2      = (const float*)d_in[32];
    const float* b2      = (const float*)d_in[33];
    const float* ln2g    = (const float*)d_in[34];
    const float* ln2b    = (const float*)d_in[35];
    const float* Wout    = (const float*)d_in[36];
    const float* bout    = (const float*)d_in[37];

    float* ws = (float*)d_ws;
    float* qkvb = ws;  ws += NB*LT*768;
    float* ob   = ws;  ws += NB*LT*DD;
    float* t1   = ws;  ws += NB*LT*DD;        // also aliases PEh
    float* x2   = ws;  ws += NB*LT*DD;
    float* t2   = ws;  ws += NB*LT*DD;        // also aliases PEl
    float* hb   = ws;  ws += NB*LT*FFD;
    float* x    = ws;  ws += NB*LT*DD;
    float* Tn   = ws;  ws += 1088*1024;
    float* qr   = ws;  ws += NB*LT*NH*DD;
    float* Dcc  = ws;  ws += 8*1024*448;      // BD for char-char: [h][row][p-313]
    float* Wcomb= ws;  ws += 1024*DD;
    float* bqkv = ws;  ws += NLAYER*768;
    float* bfus4= ws;  ws += 1024;
    float* bias_vr = ws; ws += NLAYER*NH*DD;
    unsigned short* us = (unsigned short*)ws;
    unsigned short* xh  = us; us += 1024*256;
    unsigned short* xl  = us; us += 1024*256;
    unsigned short* x2h = us; us += 1024*256;
    unsigned short* x2l = us; us += 1024*256;
    unsigned short* qkvbh = us; us += 1024*768;
    unsigned short* qkvbl = us; us += 1024*768;
    unsigned short* hbh = us; us += 1024*1024;
    unsigned short* hbl = us; us += 1024*1024;
    unsigned short* obh = us; us += 1024*256;
    unsigned short* obl = us; us += 1024*256;
    unsigned short* qrh = us; us += 1024*2048;
    unsigned short* qrl = us; us += 1024*2048;
    unsigned short* Rcch = us; us += 1025*256;
    unsigned short* Rccl = us; us += 1025*256;
    unsigned short* WcombT_h = us; us += 256*1024;
    unsigned short* WcombT_l = us; us += 256*1024;
    unsigned short* WqkvT_h  = us; us += NLAYER*768*256;
    unsigned short* WqkvT_l  = us; us += NLAYER*768*256;
    unsigned short* WoT_h    = us; us += NLAYER*256*256;
    unsigned short* WoT_l    = us; us += NLAYER*256*256;
    unsigned short* W1T_h    = us; us += NLAYER*1024*256;
    unsigned short* W1T_l    = us; us += NLAYER*1024*256;
    unsigned short* W2T_h    = us; us += NLAYER*256*1024;
    unsigned short* W2T_l    = us; us += NLAYER*256*1024;
    unsigned short* WfusT_h  = us; us += 1024*256;
    unsigned short* WfusT_l  = us; us += 1024*256;
    unsigned short* WrB_h    = us; us += NLAYER*NH*256*32;
    unsigned short* WrB_l    = us; us += NLAYER*NH*256*32;
    // aliases (timeline-disjoint):
    unsigned short* Gh  = hbh;                 // [1024][1024], dead before W1 gemm
    unsigned short* Gl  = hbl;
    unsigned short* PEh = (unsigned short*)t1; // [1088][256], dead before layer loop
    unsigned short* PEl = (unsigned short*)t2;

    const int M = NB*LT;

    gather_v3<<<M, 256, 0, stream>>>(lattice, bigrams, seq_len, lex_num,
                                     bert, lat_t, big_t, Gh, Gl);
    wcomb_kernel<<<1024, 256, 0, stream>>>(Wc, bc, Wl, bl, Wcomb);
    pe_v3<<<1088, 256, 0, stream>>>(PEh, PEl);
    smallpack<<<1, 256, 0, stream>>>(bq, bk, bv, b_fus, bqkv, bfus4);
    vrbias_kernel<<<NLAYER*NH, 256, 0, stream>>>(v_bias, Wr, bias_vr);
    trans_all<<<dim3(256, 16, 7), 256, 0, stream>>>(Wcomb, Wq, Wk, Wv, Wo, W1, W2, W_fus, Wr,
        WcombT_h, WcombT_l, WqkvT_h, WqkvT_l, WoT_h, WoT_l,
        W1T_h, W1T_l, W2T_h, W2T_l, WfusT_h, WfusT_l, WrB_h, WrB_l);

    // Tn = PE @ W_fus (4 tables as column segments) + bfus4
    gemm_v3<64,false,false><<<dim3(16, 17), 256, 0, stream>>>(
        PEh, PEl, WfusT_h, WfusT_l, bfus4, nullptr, Tn, nullptr, nullptr,
        1088, 1024, 256, 256, 1024, 0, 0, 0, 0);
    rcc_split<<<1025, 256, 0, stream>>>(Tn, Rcch, Rccl);

    // embed: x = G @ Wcomb
    gemm_v3<64,false,true><<<dim3(4, 16), 256, 0, stream>>>(
        Gh, Gl, WcombT_h, WcombT_l, nullptr, nullptr, x, xh, xl,
        M, 256, 1024, 1024, 256, 0, 0, 0, 0);

    for (int l = 0; l < NLAYER; ++l) {
        gemm_v3<64,false,true><<<dim3(12, 16), 256, 0, stream>>>(
            xh, xl, WqkvT_h + l*768*256, WqkvT_l + l*768*256, bqkv + l*768, nullptr,
            qkvb, qkvbh, qkvbl, M, 768, 256, 256, 768, 0, 0, 0, 0);
        // qr[row][h][e] = Q_h @ Wr_h + (vb@Wr)_h   (block-diag MFMA, z=head; emits split)
        gemm_v3<32,false,true><<<dim3(4, 16, 8), 256, 0, stream>>>(
            qkvbh, qkvbl, WrB_h + l*8*8192, WrB_l + l*8*8192, bias_vr + l*8*256, nullptr,
            qr, qrh, qrl, M, 256, 32, 768, 2048, 32, 8192, 256, 256);
        // Dcc[h][row][p-313] = qr_h @ Rcc[313..761)^T  (char-char BD, z=head)
        gemm_v3<64,false,false><<<dim3(7, 16, 8), 256, 0, stream>>>(
            qrh, qrl, Rcch + 313*256, Rccl + 313*256, nullptr, nullptr,
            Dcc, nullptr, nullptr, M, 448, 256, 2048, 448, 256, 0, 1024*448, 0);
        attn_v4<<<M, 256, 0, stream>>>(qkvb, qr, Tn, Dcc, pos_s, pos_e,
                                       seq_len, lex_num, u_bias + l*DD, ob, obh, obl);
        gemm_v3<64,false,false><<<dim3(4, 16), 256, 0, stream>>>(
            obh, obl, WoT_h + l*65536, WoT_l + l*65536, bo + l*DD, x,
            t1, nullptr, nullptr, M, 256, 256, 256, 256, 0, 0, 0, 0);
        ln_v3<true><<<M, 256, 0, stream>>>(t1, ln1g + l*DD, ln1b + l*DD, x2, x2h, x2l);
        gemm_v3<64,true,true><<<dim3(16, 16), 256, 0, stream>>>(
            x2h, x2l, W1T_h + l*262144, W1T_l + l*262144, b1 + l*FFD, nullptr,
            hb, hbh, hbl, M, FFD, 256, 256, 1024, 0, 0, 0, 0);
        gemm_v3<64,false,false><<<dim3(4, 16), 256, 0, stream>>>(
            hbh, hbl, W2T_h + l*262144, W2T_l + l*262144, b2 + l*DD, x2,
            t2, nullptr, nullptr, M, 256, 1024, 1024, 256, 0, 0, 0, 0);
        ln_v3<true><<<M, 256, 0, stream>>>(t2, ln2g + l*DD, ln2b + l*DD, x, xh, xl);
    }
    out_kernel<<<NB*SS, 64, 0, stream>>>(x, Wout, bout, (float*)d_out);
}

// Round 9
// 470.217 us; speedup vs baseline: 1.2050x; 1.0477x over previous
//
#include <hip/hip_runtime.h>
#include <math.h>

#define NB 4
#define SS 200
#define LT 256
#define DD 256
#define NH 8
#define NLAYER 2
#define FFD 1024
#define BERTD 768
#define NEGINF -1e15f
#define SCL 0.17677669529663687f

typedef __attribute__((ext_vector_type(8))) short bf16x8;
typedef __attribute__((ext_vector_type(4))) float f32x4;
typedef __attribute__((ext_vector_type(8))) unsigned short u16x8;

__device__ inline float bf2f(unsigned short h) {
    union { unsigned int u; float f; } v; v.u = ((unsigned int)h) << 16; return v.f;
}
__device__ inline unsigned short f2bf(float x) {
    union { float f; unsigned int u; } v; v.f = x;
    unsigned int r = v.u + 0x7fffu + ((v.u >> 16) & 1u);
    return (unsigned short)(r >> 16);
}
__device__ inline void split2(float x, unsigned short& h, unsigned short& l) {
    h = f2bf(x); l = f2bf(x - bf2f(h));
}

// ---------------- gather combined embed input -> bf16 hi/lo [1024][1024] --------------
__global__ void gather_v3(const int* __restrict__ lattice, const int* __restrict__ bigrams,
                          const int* __restrict__ seq_len, const int* __restrict__ lex_num,
                          const float* __restrict__ bert, const float* __restrict__ lat_t,
                          const float* __restrict__ big_t,
                          unsigned short* __restrict__ Gh, unsigned short* __restrict__ Gl)
{
    const int row = blockIdx.x, t = threadIdx.x;
    const int b = row >> 8, l = row & 255;
    const int sl = seq_len[b], tl = sl + lex_num[b];
    const float mC = (l < sl) ? 1.f : 0.f;
    const float mL = (l >= sl && l < tl) ? 1.f : 0.f;
    const int lat = lattice[row];
    const int big = (l < SS) ? bigrams[b*SS + l] : 0;
    for (int i = t; i < 1024; i += 256) {
        float v;
        if (i < 50)        v = lat_t[lat*50 + i] * mC;
        else if (i < 100)  v = (l < SS) ? big_t[big*50 + (i-50)] * mC : 0.f;
        else if (i < 868)  v = (l < SS) ? bert[(b*SS + l)*BERTD + (i-100)] * mC : 0.f;
        else if (i < 918)  v = lat_t[lat*50 + (i-868)] * mL;
        else if (i == 918) v = mC;
        else if (i == 919) v = mL;
        else               v = 0.f;
        unsigned short hh, ll; split2(v, hh, ll);
        Gh[(size_t)row*1024 + i] = hh; Gl[(size_t)row*1024 + i] = ll;
    }
}

// ---------------- merged prep: Wcomb rows | PE rows | vrbias | small packs ------------
__global__ void prep_all(const float* __restrict__ Wc, const float* __restrict__ bc,
                         const float* __restrict__ Wl, const float* __restrict__ bl,
                         const float* __restrict__ vb, const float* __restrict__ Wr,
                         const float* __restrict__ bq, const float* __restrict__ bk,
                         const float* __restrict__ bv, const float* __restrict__ b_fus,
                         float* __restrict__ Wcomb,
                         unsigned short* __restrict__ PEh, unsigned short* __restrict__ PEl,
                         float* __restrict__ bias_vr,
                         float* __restrict__ bqkv, float* __restrict__ bfus4)
{
    const int g = blockIdx.x, t = threadIdx.x;
    if (g < 1024) {                       // Wcomb[1024][256]
        const int r = g;
        float v;
        if (r < 868)       v = Wc[r*DD + t];
        else if (r < 918)  v = Wl[(r-868)*DD + t];
        else if (r == 918) v = bc[t];
        else if (r == 919) v = bl[t];
        else               v = 0.f;
        Wcomb[r*DD + t] = v;
    } else if (g < 2112) {                // PE rows [1088][256]
        const int p = g - 1024;
        float v = 0.f;
        if (p <= 1024) {
            const float fr = expf(-(float)(t & 127) * (9.210340371976184f / 127.0f));
            const float arg = (float)p * fr;
            v = (t < 128) ? sinf(arg) : cosf(arg);
        }
        unsigned short hh, ll; split2(v, hh, ll);
        PEh[p*DD + t] = hh; PEl[p*DD + t] = ll;
    } else if (g < 2128) {                // bias_vr: 16 (l,h) rows
        const int lh = g - 2112;
        const int l = lh >> 3, h = lh & 7;
        float acc = 0.f;
        #pragma unroll 8
        for (int d = 0; d < 32; ++d)
            acc += vb[l*DD + h*32 + d] * Wr[(size_t)l*DD*DD + (h*32 + d)*DD + t];
        bias_vr[lh*DD + t] = acc;
    } else {                              // small packs
        for (int l = 0; l < NLAYER; ++l) {
            bqkv[l*768 + t]       = bq[l*DD + t];
            bqkv[l*768 + 256 + t] = bk[l*DD + t];
            bqkv[l*768 + 512 + t] = bv[l*DD + t];
        }
        bfus4[t] = b_fus[t];
        bfus4[256 + t] = 0.f; bfus4[512 + t] = 0.f; bfus4[768 + t] = 0.f;
    }
}

// ---------------- merged transpose+split of all GEMM weights (flat 2176 tiles) --------
__global__ void trans_all2(const float* __restrict__ Wcomb, const float* __restrict__ Wq,
                           const float* __restrict__ Wk, const float* __restrict__ Wv,
                           const float* __restrict__ Wo, const float* __restrict__ W1,
                           const float* __restrict__ W2, const float* __restrict__ Wfus,
                           const float* __restrict__ Wr,
                           unsigned short* WcombT_h, unsigned short* WcombT_l,
                           unsigned short* WqkvT_h,  unsigned short* WqkvT_l,
                           unsigned short* WoT_h,    unsigned short* WoT_l,
                           unsigned short* W1T_h,    unsigned short* W1T_l,
                           unsigned short* W2T_h,    unsigned short* W2T_l,
                           unsigned short* WfusT_h,  unsigned short* WfusT_l,
                           unsigned short* WrB_h,    unsigned short* WrB_l)
{
    int g = blockIdx.x;
    const int t = threadIdx.x;
    const float* src; unsigned short *dh, *dl; int K, N, tile;
    if (g < 256)        { K=1024; N=256;  src=Wcomb; dh=WcombT_h; dl=WcombT_l; tile=g; }
    else if (g < 640)   { g -= 256; int j = g >> 6; tile = g & 63; int l = j/3, s = j%3;
                          K=256; N=256;
                          src = (s==0 ? Wq : s==1 ? Wk : Wv) + l*65536;
                          dh = WqkvT_h + (l*768 + s*256)*256; dl = WqkvT_l + (l*768 + s*256)*256; }
    else if (g < 768)   { g -= 640; int y = g >> 6; tile = g & 63; K=256; N=256;
                          src = Wo + y*65536;  dh = WoT_h + y*65536;  dl = WoT_l + y*65536; }
    else if (g < 1280)  { g -= 768; int y = g >> 8; tile = g & 255; K=256; N=1024;
                          src = W1 + y*262144; dh = W1T_h + y*262144; dl = W1T_l + y*262144; }
    else if (g < 1792)  { g -= 1280; int y = g >> 8; tile = g & 255; K=1024; N=256;
                          src = W2 + y*262144; dh = W2T_h + y*262144; dl = W2T_l + y*262144; }
    else if (g < 2048)  { g -= 1792; int y = g >> 6; tile = g & 63; K=256; N=256;
                          src = Wfus + y*65536; dh = WfusT_h + y*65536; dl = WfusT_l + y*65536; }
    else                { g -= 2048; int y = g >> 3; tile = g & 7; int l = y >> 3, h = y & 7;
                          K=32; N=256;
                          src = Wr + (size_t)l*65536 + h*32*256;
                          dh = WrB_h + y*8192; dl = WrB_l + y*8192; }
    const int tiles_x = N >> 5;
    const int tn = tile % tiles_x, tk = tile / tiles_x;
    __shared__ float s[32][33];
    const int lr = t >> 5, lc = t & 31;
    #pragma unroll
    for (int i = 0; i < 4; ++i)
        s[lr + 8*i][lc] = src[(size_t)(tk*32 + lr + 8*i)*N + tn*32 + lc];
    __syncthreads();
    #pragma unroll
    for (int i = 0; i < 4; ++i) {
        const int n = tn*32 + lr + 8*i, k = tk*32 + lc;
        unsigned short hh, ll; split2(s[lc][lr + 8*i], hh, ll);
        dh[(size_t)n*K + k] = hh;
        dl[(size_t)n*K + k] = ll;
    }
}

// ---------------- MFMA GEMM v3: A pre-split bf16 [M][lda], B pre-split [N][K] ---------
template<int BK, bool RELU, bool EMIT>
__global__ __launch_bounds__(256) void gemm_v3(
    const unsigned short* __restrict__ Ah, const unsigned short* __restrict__ Al,
    const unsigned short* __restrict__ Bh, const unsigned short* __restrict__ Bl,
    const float* __restrict__ bias, const float* __restrict__ resid,
    float* __restrict__ C, unsigned short* __restrict__ Ch, unsigned short* __restrict__ Cl,
    int M, int N, int K, int lda, int ldc, int aZ, int bZ, int cZ, int biasZ)
{
    constexpr int LDK = BK + 8;
    __shared__ unsigned short AhS[64*LDK], AlS[64*LDK];
    __shared__ unsigned short BhS[64*LDK], BlS[64*LDK];
    const int z = blockIdx.z;
    Ah += (size_t)z * aZ; Al += (size_t)z * aZ;
    Bh += (size_t)z * bZ; Bl += (size_t)z * bZ;
    C  += (size_t)z * cZ;
    if (EMIT) { Ch += (size_t)z * cZ; Cl += (size_t)z * cZ; }
    if (bias) bias += (size_t)z * biasZ;

    const int t = threadIdx.x;
    const int row0 = blockIdx.y * 64, col0 = blockIdx.x * 64;
    const int lane = t & 63, w = t >> 6;
    const int wm = w >> 1, wn = w & 1;
    const int fr = lane & 15, fq = lane >> 4;
    const int sr = t >> 2, sc0 = (t & 3) * (BK/4);

    f32x4 acc[2][2];
    #pragma unroll
    for (int i = 0; i < 2; ++i)
        #pragma unroll
        for (int j = 0; j < 2; ++j) acc[i][j] = (f32x4){0.f, 0.f, 0.f, 0.f};

    for (int k0 = 0; k0 < K; k0 += BK) {
        #pragma unroll
        for (int i = 0; i < BK/32; ++i) {
            const int c = sc0 + i*8;
            *(u16x8*)&AhS[sr*LDK + c] = *(const u16x8*)&Ah[(size_t)(row0+sr)*lda + k0 + c];
            *(u16x8*)&AlS[sr*LDK + c] = *(const u16x8*)&Al[(size_t)(row0+sr)*lda + k0 + c];
            *(u16x8*)&BhS[sr*LDK + c] = *(const u16x8*)&Bh[(size_t)(col0+sr)*K + k0 + c];
            *(u16x8*)&BlS[sr*LDK + c] = *(const u16x8*)&Bl[(size_t)(col0+sr)*K + k0 + c];
        }
        __syncthreads();
        #pragma unroll
        for (int ks = 0; ks < BK/32; ++ks) {
            const int ko = ks*32 + fq*8;
            const bf16x8 ah0 = *(const bf16x8*)&AhS[(wm*32 + fr)*LDK + ko];
            const bf16x8 ah1 = *(const bf16x8*)&AhS[(wm*32 + 16 + fr)*LDK + ko];
            const bf16x8 al0 = *(const bf16x8*)&AlS[(wm*32 + fr)*LDK + ko];
            const bf16x8 al1 = *(const bf16x8*)&AlS[(wm*32 + 16 + fr)*LDK + ko];
            #pragma unroll
            for (int nt = 0; nt < 2; ++nt) {
                const int nb = (wn*32 + nt*16 + fr)*LDK + ko;
                const bf16x8 bh = *(const bf16x8*)&BhS[nb];
                const bf16x8 bl = *(const bf16x8*)&BlS[nb];
                acc[0][nt] = __builtin_amdgcn_mfma_f32_16x16x32_bf16(ah0, bh, acc[0][nt], 0, 0, 0);
                acc[0][nt] = __builtin_amdgcn_mfma_f32_16x16x32_bf16(ah0, bl, acc[0][nt], 0, 0, 0);
                acc[0][nt] = __builtin_amdgcn_mfma_f32_16x16x32_bf16(al0, bh, acc[0][nt], 0, 0, 0);
                acc[1][nt] = __builtin_amdgcn_mfma_f32_16x16x32_bf16(ah1, bh, acc[1][nt], 0, 0, 0);
                acc[1][nt] = __builtin_amdgcn_mfma_f32_16x16x32_bf16(ah1, bl, acc[1][nt], 0, 0, 0);
                acc[1][nt] = __builtin_amdgcn_mfma_f32_16x16x32_bf16(al1, bh, acc[1][nt], 0, 0, 0);
            }
        }
        __syncthreads();
    }
    #pragma unroll
    for (int mt = 0; mt < 2; ++mt) {
        #pragma unroll
        for (int nt = 0; nt < 2; ++nt) {
            const int gcol = col0 + wn*32 + nt*16 + fr;
            const float bv = bias ? bias[gcol] : 0.f;
            #pragma unroll
            for (int r = 0; r < 4; ++r) {
                const int grow = row0 + wm*32 + mt*16 + fq*4 + r;
                float v = acc[mt][nt][r] + bv;
                if (resid) v += resid[(size_t)grow*ldc + gcol];
                if (RELU)  v = fmaxf(v, 0.f);
                C[(size_t)grow*ldc + gcol] = v;
                if (EMIT) {
                    unsigned short hh, ll; split2(v, hh, ll);
                    Ch[(size_t)grow*ldc + gcol] = hh;
                    Cl[(size_t)grow*ldc + gcol] = ll;
                }
            }
        }
    }
}

// ---------------- Rcc split bf16: relu(sum of 4 segments of Tn[p]) --------------------
__global__ void rcc_split(const float* __restrict__ Tn,
                          unsigned short* __restrict__ Rh, unsigned short* __restrict__ Rl)
{
    const int p = blockIdx.x, t = threadIdx.x;
    const float v = Tn[(size_t)p*1024 + t] + Tn[(size_t)p*1024 + 256 + t]
                  + Tn[(size_t)p*1024 + 512 + t] + Tn[(size_t)p*1024 + 768 + t];
    unsigned short hh, ll; split2(fmaxf(v, 0.f), hh, ll);
    Rh[p*DD + t] = hh; Rl[p*DD + t] = ll;
}

// ---------------- fused attention v5: slim LDS (4 blocks/CU), 2 barriers/tile ---------
__global__ __launch_bounds__(256) void attn_v5(
    const float* __restrict__ qkvb, const float* __restrict__ qr,
    const float* __restrict__ Tn, const float* __restrict__ Dcc,
    const int* __restrict__ pos_s, const int* __restrict__ pos_e,
    const int* __restrict__ seq_len, const int* __restrict__ lex_num,
    const float* __restrict__ u, float* __restrict__ ob,
    unsigned short* __restrict__ obh, unsigned short* __restrict__ obl)
{
    __shared__ float qu[256];
    __shared__ float qrl[NH][260];
    __shared__ float sc[NH][264];
    __shared__ float relb[16][260];
    __shared__ float red[1024];
    float* DccL = &relb[0][0];               // phase-1 alias (8*200 = 1600 < 16*260)

    const int t = threadIdx.x, row = blockIdx.x;
    const int b = row >> 8, q = row & 255;
    const int totlen = seq_len[b] + lex_num[b];
    if (q >= SS && q >= totlen) {
        ob[row*DD + t] = 0.f; obh[row*DD + t] = 0; obl[row*DD + t] = 0;
        return;
    }
    const bool qc = (q < SS);
    const int gstart = qc ? SS : 0;          // first k needing 4-table gather

    qu[t] = qkvb[(size_t)row*768 + t] + u[t];
    if (totlen > gstart) {
        #pragma unroll
        for (int h = 0; h < NH; ++h) qrl[h][t] = qr[(size_t)row*2048 + h*256 + t];
    }
    if (qc && t < SS) {
        #pragma unroll
        for (int h = 0; h < NH; ++h)
            DccL[h*SS + t] = Dcc[((size_t)h*1024 + row)*448 + q + t];
    }
    const int ps_q = pos_s[row], pe_q = pos_e[row];
    const int* psb = pos_s + b*LT;
    const int* peb = pos_e + b*LT;
    __syncthreads();

    {   // phase 1: AC for all k (unscaled into sc); char-char finalized via Dcc
        const int h = t & 7, k0 = t >> 3;
        const float4* qp = (const float4*)&qu[h*32];
        #pragma unroll
        for (int pass = 0; pass < 8; ++pass) {
            const int kg = pass*32 + k0;
            if (kg < totlen) {
                const float4* kp = (const float4*)&qkvb[(size_t)(b*LT + kg)*768 + 256 + h*32];
                float ac = 0.f;
                #pragma unroll
                for (int d4 = 0; d4 < 8; ++d4) {
                    const float4 kv = kp[d4], qv = qp[d4];
                    ac += kv.x*qv.x + kv.y*qv.y + kv.z*qv.z + kv.w*qv.w;
                }
                if (qc && kg < SS) sc[h][kg] = (ac + DccL[h*SS + (SS-1) - kg]) * SCL;
                else               sc[h][kg] = ac;          // BD added in phase 2
            } else {
                sc[h][kg] = NEGINF;
            }
        }
    }
    __syncthreads();                          // also releases DccL alias for relb

    // phase 2: 16-row gather tiles (lex-involved (q,k) only), 2 barriers per tile
    const int gs0 = gstart & ~15;
    for (int K0 = gs0; K0 < totlen; K0 += 16) {
        {   // stage: 16 threads per row, fully coalesced 256B lines
            const int r = t >> 4, c4 = (t & 15)*4;
            const int kg = K0 + r;
            if (kg >= gstart && kg < totlen) {
                const int sk = psb[kg], ek = peb[kg];
                const float* t0 = Tn + (size_t)(ps_q - sk + 512)*1024;
                const float* t1 = Tn + (size_t)(ps_q - ek + 512)*1024 + 256;
                const float* t2 = Tn + (size_t)(pe_q - sk + 512)*1024 + 512;
                const float* t3 = Tn + (size_t)(pe_q - ek + 512)*1024 + 768;
                #pragma unroll
                for (int i = 0; i < 4; ++i) {
                    const int e = i*64 + c4;
                    const float4 a = *(const float4*)&t0[e];
                    const float4 bb = *(const float4*)&t1[e];
                    const float4 c = *(const float4*)&t2[e];
                    const float4 d = *(const float4*)&t3[e];
                    float4 v;
                    v.x = fmaxf(a.x + bb.x + c.x + d.x, 0.f);
                    v.y = fmaxf(a.y + bb.y + c.y + d.y, 0.f);
                    v.z = fmaxf(a.z + bb.z + c.z + d.z, 0.f);
                    v.w = fmaxf(a.w + bb.w + c.w + d.w, 0.f);
                    *(float4*)&relb[r][e] = v;
                }
            }
        }
        __syncthreads();
        {   // dot: thread (h = t>>5, half = (t>>4)&1, k = t&15); half-dots + shfl combine
            const int k = t & 15, half = (t >> 4) & 1, h = t >> 5;
            const int kg = K0 + k;
            float s = 0.f;
            if (kg >= gstart && kg < totlen) {
                const float4* rp = (const float4*)&relb[k][half*128];
                const float4* qp = (const float4*)&qrl[h][half*128];
                #pragma unroll
                for (int e4 = 0; e4 < 32; ++e4) {
                    const float4 r4 = rp[e4], q4 = qp[e4];
                    s += r4.x*q4.x + r4.y*q4.y + r4.z*q4.z + r4.w*q4.w;
                }
            }
            s += __shfl_xor(s, 16);           // combine halves (same wave)
            if (half == 0 && kg >= gstart && kg < totlen)
                sc[h][kg] = (sc[h][kg] + s) * SCL;
        }
        __syncthreads();
    }

    {   // softmax: 8 lane-groups of 32, one head each
        const int g = t >> 5, ln = t & 31;
        float vals[8];
        float m = -INFINITY;
        #pragma unroll
        for (int i = 0; i < 8; ++i) {
            const int kidx = ln + 32*i;
            vals[i] = (kidx < totlen) ? sc[g][kidx] : NEGINF;
            m = fmaxf(m, vals[i]);
        }
        #pragma unroll
        for (int off = 16; off >= 1; off >>= 1) m = fmaxf(m, __shfl_xor(m, off, 32));
        float sum = 0.f;
        #pragma unroll
        for (int i = 0; i < 8; ++i) { vals[i] = expf(vals[i] - m); sum += vals[i]; }
        #pragma unroll
        for (int off = 16; off >= 1; off >>= 1) sum += __shfl_xor(sum, off, 32);
        const float inv = 1.0f / sum;
        #pragma unroll
        for (int i = 0; i < 8; ++i) sc[g][ln + 32*i] = vals[i] * inv;
    }
    __syncthreads();
    {   // PV
        const int j4 = (t & 63)*4, kr = t >> 6;
        const int h = j4 >> 5;
        float4 acc = make_float4(0.f, 0.f, 0.f, 0.f);
        const float* vp = qkvb + (size_t)(b*LT)*768 + 512 + j4;
        for (int k = kr; k < totlen; k += 4) {
            const float p = sc[h][k];
            const float4 v = *(const float4*)&vp[(size_t)k*768];
            acc.x += p*v.x; acc.y += p*v.y; acc.z += p*v.z; acc.w += p*v.w;
        }
        *(float4*)&red[kr*256 + j4] = acc;
    }
    __syncthreads();
    {
        const float v = red[t] + red[256 + t] + red[512 + t] + red[768 + t];
        ob[row*DD + t] = v;
        unsigned short hh, ll; split2(v, hh, ll);
        obh[row*DD + t] = hh; obl[row*DD + t] = ll;
    }
}

// ---------------- LayerNorm over last dim (256), optional bf16 emit -------------------
template<bool EMIT>
__global__ void ln_v3(const float* __restrict__ in, const float* __restrict__ g,
                      const float* __restrict__ bb, float* __restrict__ out,
                      unsigned short* __restrict__ oh, unsigned short* __restrict__ ol)
{
    __shared__ float red[4];
    const int t = threadIdx.x, row = blockIdx.x;
    const float v = in[row*DD + t];
    float s = v;
    #pragma unroll
    for (int off = 32; off >= 1; off >>= 1) s += __shfl_xor(s, off, 64);
    if ((t & 63) == 0) red[t >> 6] = s;
    __syncthreads();
    const float m = (red[0] + red[1] + red[2] + red[3]) * (1.0f/256.0f);
    __syncthreads();
    const float d = v - m;
    float s2 = d*d;
    #pragma unroll
    for (int off = 32; off >= 1; off >>= 1) s2 += __shfl_xor(s2, off, 64);
    if ((t & 63) == 0) red[t >> 6] = s2;
    __syncthreads();
    const float var = (red[0] + red[1] + red[2] + red[3]) * (1.0f/256.0f);
    const float o = d * rsqrtf(var + 1e-5f) * g[t] + bb[t];
    out[row*DD + t] = o;
    if (EMIT) {
        unsigned short hh, ll; split2(o, hh, ll);
        oh[row*DD + t] = hh; ol[row*DD + t] = ll;
    }
}

// ---------------- final: logits[b,s] = x[b,s] @ Wout + bout ---------------------------
__global__ void out_kernel(const float* __restrict__ x, const float* __restrict__ Wout,
                           const float* __restrict__ bout, float* __restrict__ out)
{
    __shared__ float xs[256];
    const int t = threadIdx.x, row = blockIdx.x;
    const int b = row / SS, s = row % SS;
    const float* xr = x + (b*LT + s)*DD;
    for (int i = t; i < DD; i += 64) xs[i] = xr[i];
    __syncthreads();
    if (t < 20) {
        float acc = bout[t];
        for (int d = 0; d < DD; ++d) acc += xs[d] * Wout[d*20 + t];
        out[row*20 + t] = acc;
    }
}

extern "C" void kernel_launch(void* const* d_in, const int* in_sizes, int n_in,
                              void* d_out, int out_size, void* d_ws, size_t ws_size,
                              hipStream_t stream)
{
    const int*   lattice = (const int*)d_in[0];
    const int*   bigrams = (const int*)d_in[1];
    const int*   seq_len = (const int*)d_in[2];
    const int*   lex_num = (const int*)d_in[3];
    const int*   pos_s   = (const int*)d_in[4];
    const int*   pos_e   = (const int*)d_in[5];
    const float* bert    = (const float*)d_in[7];
    const float* lat_t   = (const float*)d_in[8];
    const float* big_t   = (const float*)d_in[9];
    const float* Wc      = (const float*)d_in[10];
    const float* bc      = (const float*)d_in[11];
    const float* Wl      = (const float*)d_in[12];
    const float* bl      = (const float*)d_in[13];
    const float* W_fus   = (const float*)d_in[14];
    const float* b_fus   = (const float*)d_in[15];
    const float* Wq      = (const float*)d_in[16];
    const float* bq      = (const float*)d_in[17];
    const float* Wk      = (const float*)d_in[18];
    const float* bk      = (const float*)d_in[19];
    const float* Wv      = (const float*)d_in[20];
    const float* bv      = (const float*)d_in[21];
    const float* Wr      = (const float*)d_in[22];
    /* d_in[23] br: dropped — constant over k, softmax shift-invariant */
    const float* u_bias  = (const float*)d_in[24];
    const float* v_bias  = (const float*)d_in[25];
    const float* Wo      = (const float*)d_in[26];
    const float* bo      = (const float*)d_in[27];
    const float* ln1g    = (const float*)d_in[28];
    const float* ln1b    = (const float*)d_in[29];
    const float* W1      = (const float*)d_in[30];
    const float* b1      = (const float*)d_in[31];
    const float* W2      = (const float*)d_in[32];
    const float* b2      = (const float*)d_in[33];
    const float* ln2g    = (const float*)d_in[34];
    const float* ln2b    = (const float*)d_in[35];
    const float* Wout    = (const float*)d_in[36];
    const float* bout    = (const float*)d_in[37];

    float* ws = (float*)d_ws;
    float* qkvb = ws;  ws += NB*LT*768;
    float* ob   = ws;  ws += NB*LT*DD;
    float* t1   = ws;  ws += NB*LT*DD;        // also aliases PEh
    float* x2   = ws;  ws += NB*LT*DD;
    float* t2   = ws;  ws += NB*LT*DD;        // also aliases PEl
    float* hb   = ws;  ws += NB*LT*FFD;
    float* x    = ws;  ws += NB*LT*DD;
    float* Tn   = ws;  ws += 1088*1024;
    float* qr   = ws;  ws += NB*LT*NH*DD;
    float* Dcc  = ws;  ws += 8*1024*448;      // BD for char-char: [h][row][p-313]
    float* Wcomb= ws;  ws += 1024*DD;
    float* bqkv = ws;  ws += NLAYER*768;
    float* bfus4= ws;  ws += 1024;
    float* bias_vr = ws; ws += NLAYER*NH*DD;
    unsigned short* us = (unsigned short*)ws;
    unsigned short* xh  = us; us += 1024*256;
    unsigned short* xl  = us; us += 1024*256;
    unsigned short* x2h = us; us += 1024*256;
    unsigned short* x2l = us; us += 1024*256;
    unsigned short* qkvbh = us; us += 1024*768;
    unsigned short* qkvbl = us; us += 1024*768;
    unsigned short* hbh = us; us += 1024*1024;
    unsigned short* hbl = us; us += 1024*1024;
    unsigned short* obh = us; us += 1024*256;
    unsigned short* obl = us; us += 1024*256;
    unsigned short* qrh = us; us += 1024*2048;
    unsigned short* qrl = us; us += 1024*2048;
    unsigned short* Rcch = us; us += 1025*256;
    unsigned short* Rccl = us; us += 1025*256;
    unsigned short* WcombT_h = us; us += 256*1024;
    unsigned short* WcombT_l = us; us += 256*1024;
    unsigned short* WqkvT_h  = us; us += NLAYER*768*256;
    unsigned short* WqkvT_l  = us; us += NLAYER*768*256;
    unsigned short* WoT_h    = us; us += NLAYER*256*256;
    unsigned short* WoT_l    = us; us += NLAYER*256*256;
    unsigned short* W1T_h    = us; us += NLAYER*1024*256;
    unsigned short* W1T_l    = us; us += NLAYER*1024*256;
    unsigned short* W2T_h    = us; us += NLAYER*256*1024;
    unsigned short* W2T_l    = us; us += NLAYER*256*1024;
    unsigned short* WfusT_h  = us; us += 1024*256;
    unsigned short* WfusT_l  = us; us += 1024*256;
    unsigned short* WrB_h    = us; us += NLAYER*NH*256*32;
    unsigned short* WrB_l    = us; us += NLAYER*NH*256*32;
    // aliases (timeline-disjoint):
    unsigned short* Gh  = hbh;                 // [1024][1024], dead before W1 gemm
    unsigned short* Gl  = hbl;
    unsigned short* PEh = (unsigned short*)t1; // [1088][256], dead before layer loop
    unsigned short* PEl = (unsigned short*)t2;

    const int M = NB*LT;

    gather_v3<<<M, 256, 0, stream>>>(lattice, bigrams, seq_len, lex_num,
                                     bert, lat_t, big_t, Gh, Gl);
    prep_all<<<2129, 256, 0, stream>>>(Wc, bc, Wl, bl, v_bias, Wr, bq, bk, bv, b_fus,
                                       Wcomb, PEh, PEl, bias_vr, bqkv, bfus4);
    trans_all2<<<2176, 256, 0, stream>>>(Wcomb, Wq, Wk, Wv, Wo, W1, W2, W_fus, Wr,
        WcombT_h, WcombT_l, WqkvT_h, WqkvT_l, WoT_h, WoT_l,
        W1T_h, W1T_l, W2T_h, W2T_l, WfusT_h, WfusT_l, WrB_h, WrB_l);

    // Tn = PE @ W_fus (4 tables as column segments) + bfus4
    gemm_v3<64,false,false><<<dim3(16, 17), 256, 0, stream>>>(
        PEh, PEl, WfusT_h, WfusT_l, bfus4, nullptr, Tn, nullptr, nullptr,
        1088, 1024, 256, 256, 1024, 0, 0, 0, 0);
    rcc_split<<<1025, 256, 0, stream>>>(Tn, Rcch, Rccl);

    // embed: x = G @ Wcomb
    gemm_v3<64,false,true><<<dim3(4, 16), 256, 0, stream>>>(
        Gh, Gl, WcombT_h, WcombT_l, nullptr, nullptr, x, xh, xl,
        M, 256, 1024, 1024, 256, 0, 0, 0, 0);

    for (int l = 0; l < NLAYER; ++l) {
        gemm_v3<64,false,true><<<dim3(12, 16), 256, 0, stream>>>(
            xh, xl, WqkvT_h + l*768*256, WqkvT_l + l*768*256, bqkv + l*768, nullptr,
            qkvb, qkvbh, qkvbl, M, 768, 256, 256, 768, 0, 0, 0, 0);
        // qr[row][h][e] = Q_h @ Wr_h + (vb@Wr)_h   (block-diag MFMA, z=head; emits split)
        gemm_v3<32,false,true><<<dim3(4, 16, 8), 256, 0, stream>>>(
            qkvbh, qkvbl, WrB_h + l*8*8192, WrB_l + l*8*8192, bias_vr + l*8*256, nullptr,
            qr, qrh, qrl, M, 256, 32, 768, 2048, 32, 8192, 256, 256);
        // Dcc[h][row][p-313] = qr_h @ Rcc[313..761)^T  (char-char BD, z=head)
        gemm_v3<64,false,false><<<dim3(7, 16, 8), 256, 0, stream>>>(
            qrh, qrl, Rcch + 313*256, Rccl + 313*256, nullptr, nullptr,
            Dcc, nullptr, nullptr, M, 448, 256, 2048, 448, 256, 0, 1024*448, 0);
        attn_v5<<<M, 256, 0, stream>>>(qkvb, qr, Tn, Dcc, pos_s, pos_e,
                                       seq_len, lex_num, u_bias + l*DD, ob, obh, obl);
        gemm_v3<64,false,false><<<dim3(4, 16), 256, 0, stream>>>(
            obh, obl, WoT_h + l*65536, WoT_l + l*65536, bo + l*DD, x,
            t1, nullptr, nullptr, M, 256, 256, 256, 256, 0, 0, 0, 0);
        ln_v3<true><<<M, 256, 0, stream>>>(t1, ln1g + l*DD, ln1b + l*DD, x2, x2h, x2l);
        gemm_v3<64,true,true><<<dim3(16, 16), 256, 0, stream>>>(
            x2h, x2l, W1T_h + l*262144, W1T_l + l*262144, b1 + l*FFD, nullptr,
            hb, hbh, hbl, M, FFD, 256, 256, 1024, 0, 0, 0, 0);
        gemm_v3<64,false,false><<<dim3(4, 16), 256, 0, stream>>>(
            hbh, hbl, W2T_h + l*262144, W2T_l + l*262144, b2 + l*DD, x2,
            t2, nullptr, nullptr, M, 256, 1024, 1024, 256, 0, 0, 0, 0);
        ln_v3<true><<<M, 256, 0, stream>>>(t2, ln2g + l*DD, ln2b + l*DD, x, xh, xl);
    }
    out_kernel<<<NB*SS, 64, 0, stream>>>(x, Wout, bout, (float*)d_out);
}